// Round 3
// baseline (1452.927 us; speedup 1.0000x reference)
//
#include <hip/hip_runtime.h>
#include <hip/hip_bf16.h>
#include <stdint.h>

#define T_TOK 8192
#define DIM   1024
#define FDIM  4096
#define NEXP  8
#define TKROWS (T_TOK * 2)   // total routed rows (top-2)

typedef float f32x4 __attribute__((ext_vector_type(4)));
typedef short s16x8 __attribute__((ext_vector_type(8)));

#define GLDS16(g, l) __builtin_amdgcn_global_load_lds(                         \
    (const __attribute__((address_space(1))) void*)(g),                        \
    (__attribute__((address_space(3))) void*)(l), 16, 0, 0)

static __device__ __forceinline__ unsigned short f2bf(float f) {
    unsigned int u = __float_as_uint(f);
    unsigned int r = u + 0x7FFFu + ((u >> 16) & 1u);
    return (unsigned short)(r >> 16);
}
static __device__ __forceinline__ float bf2f(unsigned short s) {
    return __uint_as_float((unsigned int)s << 16);
}

// ---- x f32 -> bf16 ----------------------------------------------------------
__global__ __launch_bounds__(256) void k_convert_x(const float4* __restrict__ x,
                                                   uint4* __restrict__ xb) {
    int i = blockIdx.x * 256 + threadIdx.x;      // each thread: 8 floats
    float4 a = x[2 * i], b = x[2 * i + 1];
    uint4 o;
    o.x = f2bf(a.x) | ((unsigned)f2bf(a.y) << 16);
    o.y = f2bf(a.z) | ((unsigned)f2bf(a.w) << 16);
    o.z = f2bf(b.x) | ((unsigned)f2bf(b.y) << 16);
    o.w = f2bf(b.z) | ((unsigned)f2bf(b.w) << 16);
    xb[i] = o;
}

// ---- weight transpose+convert: w [E][K][N] f32 -> wt [E][N][K] bf16 ---------
__global__ __launch_bounds__(256) void k_transpose(const float* __restrict__ w,
                                                   ushort* __restrict__ wt,
                                                   int K, int N) {
    int nt = N >> 6, ktl = K >> 6;
    int bid = blockIdx.x;
    int e = bid / (ktl * nt);
    int r = bid % (ktl * nt);
    int kb = r / nt, nb = r % nt;
    __shared__ ushort tile[64][65];
    const float* we = w + (size_t)e * K * N + (size_t)(kb * 64) * N + nb * 64;
    int t = threadIdx.x;
#pragma unroll
    for (int g = 0; g < 4; ++g) {
        int idx = t + g * 256;
        int row = idx >> 4, c4 = idx & 15;
        float4 v = *(const float4*)(we + (size_t)row * N + c4 * 4);
        tile[row][c4 * 4 + 0] = f2bf(v.x);
        tile[row][c4 * 4 + 1] = f2bf(v.y);
        tile[row][c4 * 4 + 2] = f2bf(v.z);
        tile[row][c4 * 4 + 3] = f2bf(v.w);
    }
    __syncthreads();
    ushort* wte = wt + (size_t)e * K * N + (size_t)(nb * 64) * K + kb * 64;
#pragma unroll
    for (int g = 0; g < 4; ++g) {
        int idx = t + g * 256;
        int n = idx >> 4, k4 = idx & 15;
        ushort4 o4;
        o4.x = tile[k4 * 4 + 0][n];
        o4.y = tile[k4 * 4 + 1][n];
        o4.z = tile[k4 * 4 + 2][n];
        o4.w = tile[k4 * 4 + 3][n];
        *(ushort4*)(wte + (size_t)n * K + k4 * 4) = o4;
    }
}

// ---- router: softmax(x @ gate_w + gate_b), top-2 ----------------------------
__global__ __launch_bounds__(256) void k_router(const float* __restrict__ x,
                                                const float* __restrict__ gw,
                                                const float* __restrict__ gb,
                                                int* __restrict__ idx_arr,
                                                float* __restrict__ w_arr,
                                                int* __restrict__ cnt) {
    int lane = threadIdx.x & 63, w = threadIdx.x >> 6;
    int tok = blockIdx.x * 4 + w;
    const float* xr = x + (size_t)tok * DIM;
    float acc[8];
#pragma unroll
    for (int e = 0; e < 8; ++e) acc[e] = 0.f;
    for (int it = 0; it < DIM / 64; ++it) {
        int d = it * 64 + lane;
        float xv = xr[d];
        const float4* g = (const float4*)(gw + (size_t)d * 8);
        float4 g0 = g[0], g1 = g[1];
        acc[0] += xv * g0.x; acc[1] += xv * g0.y;
        acc[2] += xv * g0.z; acc[3] += xv * g0.w;
        acc[4] += xv * g1.x; acc[5] += xv * g1.y;
        acc[6] += xv * g1.z; acc[7] += xv * g1.w;
    }
#pragma unroll
    for (int off = 32; off; off >>= 1)
#pragma unroll
        for (int e = 0; e < 8; ++e) acc[e] += __shfl_xor(acc[e], off);
    if (lane == 0) {
        float l[8], m = -1e30f;
#pragma unroll
        for (int e = 0; e < 8; ++e) { l[e] = acc[e] + gb[e]; m = fmaxf(m, l[e]); }
        float s = 0.f, p[8];
#pragma unroll
        for (int e = 0; e < 8; ++e) { p[e] = expf(l[e] - m); s += p[e]; }
        float inv = 1.f / s;
#pragma unroll
        for (int e = 0; e < 8; ++e) p[e] *= inv;
        int i0 = 0;
#pragma unroll
        for (int e = 1; e < 8; ++e) if (p[e] > p[i0]) i0 = e;
        int i1 = (i0 == 0) ? 1 : 0;
#pragma unroll
        for (int e = 0; e < 8; ++e) if (e != i0 && p[e] > p[i1]) i1 = e;
        idx_arr[tok * 2 + 0] = i0;  w_arr[tok * 2 + 0] = p[i0];
        idx_arr[tok * 2 + 1] = i1;  w_arr[tok * 2 + 1] = p[i1];
        atomicAdd(&cnt[i0], 1);
        atomicAdd(&cnt[i1], 1);
    }
}

__global__ void k_scan(const int* __restrict__ cnt, int* __restrict__ offs) {
    if (threadIdx.x == 0) {
        int s = 0;
        for (int e = 0; e < NEXP; ++e) { offs[e] = s; s += cnt[e]; }
        offs[NEXP] = s;
    }
}

__global__ __launch_bounds__(256) void k_fill(const int* __restrict__ idx_arr,
                                              const float* __restrict__ w_arr,
                                              const int* __restrict__ offs,
                                              int* __restrict__ fill,
                                              int* __restrict__ row_token,
                                              int* __restrict__ tok_row) {
    int t = blockIdx.x * 256 + threadIdx.x;
    if (t >= T_TOK) return;
#pragma unroll
    for (int k = 0; k < 2; ++k) {
        int e = idx_arr[t * 2 + k];
        int slot = atomicAdd(&fill[e], 1);
        int r = offs[e] + slot;
        row_token[r] = t;
        tok_row[t * 2 + k] = r;
    }
}

// ---- GEMM1: h = silu(x_gathered @ w1t[e]^T + b1[e])  [M=ne, N=4096, K=1024] -
// double-buffered 2-phase: STAGE(next) -> COMPUTE(cur) -> one barrier.
__global__ __launch_bounds__(256) void k_gemm1(const ushort* __restrict__ xb,
                                               const ushort* __restrict__ w1t,
                                               const float* __restrict__ b1,
                                               const int* __restrict__ cnt,
                                               const int* __restrict__ offs,
                                               const int* __restrict__ row_token,
                                               ushort* __restrict__ h) {
    int bid = blockIdx.x;
    int e  = bid >> 11;          // 32 ct * 64 rt per expert
    int ct = (bid >> 6) & 31;
    int rt = bid & 63;
    int ne = cnt[e];
    if (rt * 128 >= ne) return;
    int base = offs[e];

    __shared__ __align__(16) ushort As[2][128 * 64];
    __shared__ __align__(16) ushort Bs[2][128 * 64];

    int tid = threadIdx.x, lane = tid & 63, wid = tid >> 6;
    int wm = wid >> 1, wn = wid & 1;

    const ushort* asrc[4];
    const ushort* bsrc[4];
    int coff[4];
    const ushort* w1e = w1t + (size_t)e * FDIM * DIM;
#pragma unroll
    for (int g = 0; g < 4; ++g) {
        int c = wid * 4 + g;               // chunk 0..15 (1024 B each)
        int o = c * 1024 + lane * 16;      // byte offset in 16 KB tile
        int row = o >> 7;                  // 128 B per row (64 bf16)
        int ko  = (o & 127) >> 1;
        int grow = base + rt * 128 + row;
        grow = grow < TKROWS ? grow : TKROWS - 1;
        asrc[g] = xb + (size_t)row_token[grow] * DIM + ko;
        bsrc[g] = w1e + (size_t)(ct * 128 + row) * DIM + ko;
        coff[g] = c * 512;                 // ushort offset of chunk base
    }

    f32x4 acc[4][4] = {};
#define STAGE1(buf, kt)                                                        \
    do {                                                                       \
        _Pragma("unroll")                                                      \
        for (int g = 0; g < 4; ++g) GLDS16(asrc[g] + (kt) * 64, &As[buf][coff[g]]); \
        _Pragma("unroll")                                                      \
        for (int g = 0; g < 4; ++g) GLDS16(bsrc[g] + (kt) * 64, &Bs[buf][coff[g]]); \
    } while (0)
#define COMPUTE1(buf)                                                          \
    do {                                                                       \
        _Pragma("unroll")                                                      \
        for (int ks = 0; ks < 2; ++ks) {                                       \
            s16x8 a[4], b[4];                                                  \
            _Pragma("unroll")                                                  \
            for (int m = 0; m < 4; ++m)                                        \
                a[m] = *(const s16x8*)&As[buf][(wm * 64 + m * 16 + (lane & 15)) * 64 + ks * 32 + (lane >> 4) * 8]; \
            _Pragma("unroll")                                                  \
            for (int n = 0; n < 4; ++n)                                        \
                b[n] = *(const s16x8*)&Bs[buf][(wn * 64 + n * 16 + (lane & 15)) * 64 + ks * 32 + (lane >> 4) * 8]; \
            _Pragma("unroll")                                                  \
            for (int m = 0; m < 4; ++m)                                        \
                _Pragma("unroll")                                              \
                for (int n = 0; n < 4; ++n)                                    \
                    acc[m][n] = __builtin_amdgcn_mfma_f32_16x16x32_bf16(a[m], b[n], acc[m][n], 0, 0, 0); \
        }                                                                      \
    } while (0)

    STAGE1(0, 0);
    __syncthreads();
    int cur = 0;
    for (int kt = 0; kt < DIM / 64 - 1; ++kt) {
        STAGE1(cur ^ 1, kt + 1);   // prefetch next tile; lands under compute
        COMPUTE1(cur);
        __syncthreads();           // drains vmcnt(0)+lgkmcnt(0), one barrier/tile
        cur ^= 1;
    }
    COMPUTE1(cur);

    const float* b1e = b1 + e * FDIM + ct * 128;
#pragma unroll
    for (int m = 0; m < 4; ++m) {
#pragma unroll
        for (int r = 0; r < 4; ++r) {
            int rloc = wm * 64 + m * 16 + ((lane >> 4) << 2) + r;
            int rexp = rt * 128 + rloc;
            if (rexp >= ne) continue;
            ushort* hrow = h + (size_t)(base + rexp) * FDIM + ct * 128;
#pragma unroll
            for (int n = 0; n < 4; ++n) {
                int col = wn * 64 + n * 16 + (lane & 15);
                float v = acc[m][n][r] + b1e[col];
                float si = v / (1.f + __expf(-v));
                hrow[col] = f2bf(si);
            }
        }
    }
#undef STAGE1
#undef COMPUTE1
}

// ---- GEMM2: y[row] = h[row] @ w2t[e]^T + b2[e]   [M=ne, N=1024, K=4096] -----
__global__ __launch_bounds__(256) void k_gemm2(const ushort* __restrict__ h,
                                               const ushort* __restrict__ w2t,
                                               const float* __restrict__ b2,
                                               const int* __restrict__ cnt,
                                               const int* __restrict__ offs,
                                               ushort* __restrict__ y) {
    int bid = blockIdx.x;
    int e  = bid >> 9;           // 8 ct * 64 rt per expert
    int ct = (bid >> 6) & 7;
    int rt = bid & 63;
    int ne = cnt[e];
    if (rt * 128 >= ne) return;
    int base = offs[e];

    __shared__ __align__(16) ushort As[2][128 * 64];
    __shared__ __align__(16) ushort Bs[2][128 * 64];

    int tid = threadIdx.x, lane = tid & 63, wid = tid >> 6;
    int wm = wid >> 1, wn = wid & 1;

    const ushort* asrc[4];
    const ushort* bsrc[4];
    int coff[4];
    const ushort* w2e = w2t + (size_t)e * DIM * FDIM;
#pragma unroll
    for (int g = 0; g < 4; ++g) {
        int c = wid * 4 + g;
        int o = c * 1024 + lane * 16;
        int row = o >> 7;
        int ko  = (o & 127) >> 1;
        int grow = base + rt * 128 + row;
        grow = grow < TKROWS ? grow : TKROWS - 1;
        asrc[g] = h + (size_t)grow * FDIM + ko;
        bsrc[g] = w2e + (size_t)(ct * 128 + row) * FDIM + ko;
        coff[g] = c * 512;
    }

    f32x4 acc[4][4] = {};
#define STAGE2(buf, kt)                                                        \
    do {                                                                       \
        _Pragma("unroll")                                                      \
        for (int g = 0; g < 4; ++g) GLDS16(asrc[g] + (kt) * 64, &As[buf][coff[g]]); \
        _Pragma("unroll")                                                      \
        for (int g = 0; g < 4; ++g) GLDS16(bsrc[g] + (kt) * 64, &Bs[buf][coff[g]]); \
    } while (0)
#define COMPUTE2(buf)                                                          \
    do {                                                                       \
        _Pragma("unroll")                                                      \
        for (int ks = 0; ks < 2; ++ks) {                                       \
            s16x8 a[4], b[4];                                                  \
            _Pragma("unroll")                                                  \
            for (int m = 0; m < 4; ++m)                                        \
                a[m] = *(const s16x8*)&As[buf][(wm * 64 + m * 16 + (lane & 15)) * 64 + ks * 32 + (lane >> 4) * 8]; \
            _Pragma("unroll")                                                  \
            for (int n = 0; n < 4; ++n)                                        \
                b[n] = *(const s16x8*)&Bs[buf][(wn * 64 + n * 16 + (lane & 15)) * 64 + ks * 32 + (lane >> 4) * 8]; \
            _Pragma("unroll")                                                  \
            for (int m = 0; m < 4; ++m)                                        \
                _Pragma("unroll")                                              \
                for (int n = 0; n < 4; ++n)                                    \
                    acc[m][n] = __builtin_amdgcn_mfma_f32_16x16x32_bf16(a[m], b[n], acc[m][n], 0, 0, 0); \
        }                                                                      \
    } while (0)

    STAGE2(0, 0);
    __syncthreads();
    int cur = 0;
    for (int kt = 0; kt < FDIM / 64 - 1; ++kt) {
        STAGE2(cur ^ 1, kt + 1);
        COMPUTE2(cur);
        __syncthreads();
        cur ^= 1;
    }
    COMPUTE2(cur);

    const float* b2e = b2 + e * DIM + ct * 128;
#pragma unroll
    for (int m = 0; m < 4; ++m) {
#pragma unroll
        for (int r = 0; r < 4; ++r) {
            int rloc = wm * 64 + m * 16 + ((lane >> 4) << 2) + r;
            int rexp = rt * 128 + rloc;
            if (rexp >= ne) continue;
            ushort* yrow = y + (size_t)(base + rexp) * DIM + ct * 128;
#pragma unroll
            for (int n = 0; n < 4; ++n) {
                int col = wn * 64 + n * 16 + (lane & 15);
                yrow[col] = f2bf(acc[m][n][r] + b2e[col]);
            }
        }
    }
#undef STAGE2
#undef COMPUTE2
}

// ---- combine: out[t] = w0*y[r0] + w1*y[r1] ----------------------------------
__global__ __launch_bounds__(256) void k_combine(const ushort* __restrict__ y,
                                                 const int* __restrict__ tok_row,
                                                 const float* __restrict__ w_arr,
                                                 float* __restrict__ out) {
    int gid = blockIdx.x * 256 + threadIdx.x;   // T_TOK*DIM/8 threads
    int t = gid >> 7;                            // 128 8-elem chunks per token
    int c = gid & 127;
    int r0 = tok_row[t * 2], r1 = tok_row[t * 2 + 1];
    float w0 = w_arr[t * 2], w1 = w_arr[t * 2 + 1];
    uint4 a = *(const uint4*)(y + (size_t)r0 * DIM + c * 8);
    uint4 b = *(const uint4*)(y + (size_t)r1 * DIM + c * 8);
    float4 o0, o1;
    o0.x = w0 * bf2f(a.x & 0xFFFF) + w1 * bf2f(b.x & 0xFFFF);
    o0.y = w0 * bf2f(a.x >> 16)    + w1 * bf2f(b.x >> 16);
    o0.z = w0 * bf2f(a.y & 0xFFFF) + w1 * bf2f(b.y & 0xFFFF);
    o0.w = w0 * bf2f(a.y >> 16)    + w1 * bf2f(b.y >> 16);
    o1.x = w0 * bf2f(a.z & 0xFFFF) + w1 * bf2f(b.z & 0xFFFF);
    o1.y = w0 * bf2f(a.z >> 16)    + w1 * bf2f(b.z >> 16);
    o1.z = w0 * bf2f(a.w & 0xFFFF) + w1 * bf2f(b.w & 0xFFFF);
    o1.w = w0 * bf2f(a.w >> 16)    + w1 * bf2f(b.w >> 16);
    float4* op = (float4*)(out + (size_t)t * DIM + c * 8);
    op[0] = o0;
    op[1] = o1;
}

extern "C" void kernel_launch(void* const* d_in, const int* in_sizes, int n_in,
                              void* d_out, int out_size, void* d_ws, size_t ws_size,
                              hipStream_t stream) {
    const float* x      = (const float*)d_in[0];
    const float* gate_w = (const float*)d_in[1];
    const float* gate_b = (const float*)d_in[2];
    const float* w1     = (const float*)d_in[3];
    const float* b1     = (const float*)d_in[4];
    const float* w2     = (const float*)d_in[5];
    const float* b2     = (const float*)d_in[6];
    float* out = (float*)d_out;

    char* ws = (char*)d_ws;
    size_t o = 0;
    ushort* h  = (ushort*)(ws + o); o += (size_t)TKROWS * FDIM * 2;      // 134 MB
    ushort* wt = (ushort*)(ws + o); o += (size_t)NEXP * DIM * FDIM * 2;  // 67 MB (w1t then w2t)
    ushort* y  = (ushort*)(ws + o);                                      // 33.5 MB
    ushort* xb = y;                 o += (size_t)TKROWS * DIM * 2;       // xb (16.8MB) dies before y is written
    int*   idx_arr   = (int*)(ws + o);   o += TKROWS * 4;
    float* w_arr     = (float*)(ws + o); o += TKROWS * 4;
    int*   row_token = (int*)(ws + o);   o += TKROWS * 4;
    int*   tok_row   = (int*)(ws + o);   o += TKROWS * 4;
    int*   cnt  = (int*)(ws + o);       // 8 ints
    int*   offs = cnt + 8;              // 9 ints
    int*   fill = cnt + 24;             // 8 ints

    hipMemsetAsync(cnt, 0, 256, stream);

    k_convert_x<<<4096, 256, 0, stream>>>((const float4*)x, (uint4*)xb);
    k_router<<<T_TOK / 4, 256, 0, stream>>>(x, gate_w, gate_b, idx_arr, w_arr, cnt);
    k_scan<<<1, 64, 0, stream>>>(cnt, offs);
    k_fill<<<T_TOK / 256, 256, 0, stream>>>(idx_arr, w_arr, offs, fill, row_token, tok_row);

    k_transpose<<<NEXP * (DIM / 64) * (FDIM / 64), 256, 0, stream>>>(w1, wt, DIM, FDIM);
    k_gemm1<<<NEXP * 64 * 32, 256, 0, stream>>>(xb, wt, b1, cnt, offs, row_token, h);
    k_transpose<<<NEXP * (FDIM / 64) * (DIM / 64), 256, 0, stream>>>(w2, wt, FDIM, DIM);
    k_gemm2<<<NEXP * 64 * 8, 256, 0, stream>>>(h, wt, b2, cnt, offs, y);
    k_combine<<<T_TOK * DIM / 8 / 256, 256, 0, stream>>>(y, tok_row, w_arr, out);
}

// Round 4
// 1253.159 us; speedup vs baseline: 1.1594x; 1.1594x over previous
//
#include <hip/hip_runtime.h>
#include <hip/hip_bf16.h>
#include <stdint.h>

#define T_TOK 8192
#define DIM   1024
#define FDIM  4096
#define NEXP  8
#define TKROWS (T_TOK * 2)   // total routed rows (top-2)

typedef float f32x4 __attribute__((ext_vector_type(4)));
typedef short s16x8 __attribute__((ext_vector_type(8)));

#define GLDS16(g, l) __builtin_amdgcn_global_load_lds(                         \
    (const __attribute__((address_space(1))) void*)(g),                        \
    (__attribute__((address_space(3))) void*)(l), 16, 0, 0)

static __device__ __forceinline__ unsigned short f2bf(float f) {
    unsigned int u = __float_as_uint(f);
    unsigned int r = u + 0x7FFFu + ((u >> 16) & 1u);
    return (unsigned short)(r >> 16);
}
static __device__ __forceinline__ float bf2f(unsigned short s) {
    return __uint_as_float((unsigned int)s << 16);
}

// ---- x f32 -> bf16 ----------------------------------------------------------
__global__ __launch_bounds__(256) void k_convert_x(const float4* __restrict__ x,
                                                   uint4* __restrict__ xb) {
    int i = blockIdx.x * 256 + threadIdx.x;      // each thread: 8 floats
    float4 a = x[2 * i], b = x[2 * i + 1];
    uint4 o;
    o.x = f2bf(a.x) | ((unsigned)f2bf(a.y) << 16);
    o.y = f2bf(a.z) | ((unsigned)f2bf(a.w) << 16);
    o.z = f2bf(b.x) | ((unsigned)f2bf(b.y) << 16);
    o.w = f2bf(b.z) | ((unsigned)f2bf(b.w) << 16);
    xb[i] = o;
}

// ---- weight transpose+convert: w [E][K][N] f32 -> wt [E][N][K] bf16 ---------
__global__ __launch_bounds__(256) void k_transpose(const float* __restrict__ w,
                                                   ushort* __restrict__ wt,
                                                   int K, int N) {
    int nt = N >> 6, ktl = K >> 6;
    int bid = blockIdx.x;
    int e = bid / (ktl * nt);
    int r = bid % (ktl * nt);
    int kb = r / nt, nb = r % nt;
    __shared__ ushort tile[64][65];
    const float* we = w + (size_t)e * K * N + (size_t)(kb * 64) * N + nb * 64;
    int t = threadIdx.x;
#pragma unroll
    for (int g = 0; g < 4; ++g) {
        int idx = t + g * 256;
        int row = idx >> 4, c4 = idx & 15;
        float4 v = *(const float4*)(we + (size_t)row * N + c4 * 4);
        tile[row][c4 * 4 + 0] = f2bf(v.x);
        tile[row][c4 * 4 + 1] = f2bf(v.y);
        tile[row][c4 * 4 + 2] = f2bf(v.z);
        tile[row][c4 * 4 + 3] = f2bf(v.w);
    }
    __syncthreads();
    ushort* wte = wt + (size_t)e * K * N + (size_t)(nb * 64) * K + kb * 64;
#pragma unroll
    for (int g = 0; g < 4; ++g) {
        int idx = t + g * 256;
        int n = idx >> 4, k4 = idx & 15;
        ushort4 o4;
        o4.x = tile[k4 * 4 + 0][n];
        o4.y = tile[k4 * 4 + 1][n];
        o4.z = tile[k4 * 4 + 2][n];
        o4.w = tile[k4 * 4 + 3][n];
        *(ushort4*)(wte + (size_t)n * K + k4 * 4) = o4;
    }
}

// ---- router: softmax(x @ gate_w + gate_b), top-2 ----------------------------
__global__ __launch_bounds__(256) void k_router(const float* __restrict__ x,
                                                const float* __restrict__ gw,
                                                const float* __restrict__ gb,
                                                int* __restrict__ idx_arr,
                                                float* __restrict__ w_arr,
                                                int* __restrict__ cnt) {
    int lane = threadIdx.x & 63, w = threadIdx.x >> 6;
    int tok = blockIdx.x * 4 + w;
    const float* xr = x + (size_t)tok * DIM;
    float acc[8];
#pragma unroll
    for (int e = 0; e < 8; ++e) acc[e] = 0.f;
    for (int it = 0; it < DIM / 64; ++it) {
        int d = it * 64 + lane;
        float xv = xr[d];
        const float4* g = (const float4*)(gw + (size_t)d * 8);
        float4 g0 = g[0], g1 = g[1];
        acc[0] += xv * g0.x; acc[1] += xv * g0.y;
        acc[2] += xv * g0.z; acc[3] += xv * g0.w;
        acc[4] += xv * g1.x; acc[5] += xv * g1.y;
        acc[6] += xv * g1.z; acc[7] += xv * g1.w;
    }
#pragma unroll
    for (int off = 32; off; off >>= 1)
#pragma unroll
        for (int e = 0; e < 8; ++e) acc[e] += __shfl_xor(acc[e], off);
    if (lane == 0) {
        float l[8], m = -1e30f;
#pragma unroll
        for (int e = 0; e < 8; ++e) { l[e] = acc[e] + gb[e]; m = fmaxf(m, l[e]); }
        float s = 0.f, p[8];
#pragma unroll
        for (int e = 0; e < 8; ++e) { p[e] = expf(l[e] - m); s += p[e]; }
        float inv = 1.f / s;
#pragma unroll
        for (int e = 0; e < 8; ++e) p[e] *= inv;
        int i0 = 0;
#pragma unroll
        for (int e = 1; e < 8; ++e) if (p[e] > p[i0]) i0 = e;
        int i1 = (i0 == 0) ? 1 : 0;
#pragma unroll
        for (int e = 0; e < 8; ++e) if (e != i0 && p[e] > p[i1]) i1 = e;
        idx_arr[tok * 2 + 0] = i0;  w_arr[tok * 2 + 0] = p[i0];
        idx_arr[tok * 2 + 1] = i1;  w_arr[tok * 2 + 1] = p[i1];
        atomicAdd(&cnt[i0], 1);
        atomicAdd(&cnt[i1], 1);
    }
}

__global__ void k_scan(const int* __restrict__ cnt, int* __restrict__ offs) {
    if (threadIdx.x == 0) {
        int s = 0;
        for (int e = 0; e < NEXP; ++e) { offs[e] = s; s += cnt[e]; }
        offs[NEXP] = s;
    }
}

__global__ __launch_bounds__(256) void k_fill(const int* __restrict__ idx_arr,
                                              const float* __restrict__ w_arr,
                                              const int* __restrict__ offs,
                                              int* __restrict__ fill,
                                              int* __restrict__ row_token,
                                              int* __restrict__ tok_row) {
    int t = blockIdx.x * 256 + threadIdx.x;
    if (t >= T_TOK) return;
#pragma unroll
    for (int k = 0; k < 2; ++k) {
        int e = idx_arr[t * 2 + k];
        int slot = atomicAdd(&fill[e], 1);
        int r = offs[e] + slot;
        row_token[r] = t;
        tok_row[t * 2 + k] = r;
    }
}

// ---- GEMM1: h = silu(x_gathered @ w1t[e]^T + b1[e])  [M=ne, N=4096, K=1024] -
// counted-vmcnt pipeline: next batch of 8 global_load_lds stays in flight
// across the barriers and the compute phase (T4).
__global__ __launch_bounds__(256) void k_gemm1(const ushort* __restrict__ xb,
                                               const ushort* __restrict__ w1t,
                                               const float* __restrict__ b1,
                                               const int* __restrict__ cnt,
                                               const int* __restrict__ offs,
                                               const int* __restrict__ row_token,
                                               ushort* __restrict__ h) {
    int bid = blockIdx.x;
    int e  = bid >> 11;          // 32 ct * 64 rt per expert
    int ct = (bid >> 6) & 31;
    int rt = bid & 63;
    int ne = cnt[e];
    if (rt * 128 >= ne) return;
    int base = offs[e];

    __shared__ __align__(16) ushort As[2][128 * 64];
    __shared__ __align__(16) ushort Bs[2][128 * 64];

    int tid = threadIdx.x, lane = tid & 63, wid = tid >> 6;
    int wm = wid >> 1, wn = wid & 1;

    const ushort* asrc[4];
    const ushort* bsrc[4];
    int coff[4];
    const ushort* w1e = w1t + (size_t)e * FDIM * DIM;
#pragma unroll
    for (int g = 0; g < 4; ++g) {
        int c = wid * 4 + g;               // chunk 0..15 (1024 B each)
        int o = c * 1024 + lane * 16;      // byte offset in 16 KB tile
        int row = o >> 7;                  // 128 B per row (64 bf16)
        int ko  = (o & 127) >> 1;
        int grow = base + rt * 128 + row;
        grow = grow < TKROWS ? grow : TKROWS - 1;
        asrc[g] = xb + (size_t)row_token[grow] * DIM + ko;
        bsrc[g] = w1e + (size_t)(ct * 128 + row) * DIM + ko;
        coff[g] = c * 512;                 // ushort offset of chunk base
    }

    f32x4 acc[4][4] = {};
#define STAGE1(buf, kt)                                                        \
    do {                                                                       \
        _Pragma("unroll")                                                      \
        for (int g = 0; g < 4; ++g) GLDS16(asrc[g] + (kt) * 64, &As[buf][coff[g]]); \
        _Pragma("unroll")                                                      \
        for (int g = 0; g < 4; ++g) GLDS16(bsrc[g] + (kt) * 64, &Bs[buf][coff[g]]); \
    } while (0)
#define COMPUTE1(buf)                                                          \
    do {                                                                       \
        _Pragma("unroll")                                                      \
        for (int ks = 0; ks < 2; ++ks) {                                       \
            s16x8 a[4], b[4];                                                  \
            _Pragma("unroll")                                                  \
            for (int m = 0; m < 4; ++m)                                        \
                a[m] = *(const s16x8*)&As[buf][(wm * 64 + m * 16 + (lane & 15)) * 64 + ks * 32 + (lane >> 4) * 8]; \
            _Pragma("unroll")                                                  \
            for (int n = 0; n < 4; ++n)                                        \
                b[n] = *(const s16x8*)&Bs[buf][(wn * 64 + n * 16 + (lane & 15)) * 64 + ks * 32 + (lane >> 4) * 8]; \
            _Pragma("unroll")                                                  \
            for (int m = 0; m < 4; ++m)                                        \
                _Pragma("unroll")                                              \
                for (int n = 0; n < 4; ++n)                                    \
                    acc[m][n] = __builtin_amdgcn_mfma_f32_16x16x32_bf16(a[m], b[n], acc[m][n], 0, 0, 0); \
        }                                                                      \
    } while (0)

    STAGE1(0, 0);                               // batch 0 in flight
    int cur = 0;
    for (int kt = 0; kt < DIM / 64 - 1; ++kt) {
        STAGE1(cur ^ 1, kt + 1);                // issue next batch (8 VMEM)
        asm volatile("s_waitcnt vmcnt(8)" ::: "memory");  // wait batch kt only
        __builtin_amdgcn_sched_barrier(0);
        __builtin_amdgcn_s_barrier();           // tile[cur] visible to all waves
        COMPUTE1(cur);                          // 8 loads stay in flight here
        __builtin_amdgcn_s_barrier();           // everyone done reading buf[cur]
        cur ^= 1;
    }
    asm volatile("s_waitcnt vmcnt(0)" ::: "memory");
    __builtin_amdgcn_sched_barrier(0);
    __builtin_amdgcn_s_barrier();
    COMPUTE1(cur);

    const float* b1e = b1 + e * FDIM + ct * 128;
#pragma unroll
    for (int m = 0; m < 4; ++m) {
#pragma unroll
        for (int r = 0; r < 4; ++r) {
            int rloc = wm * 64 + m * 16 + ((lane >> 4) << 2) + r;
            int rexp = rt * 128 + rloc;
            if (rexp >= ne) continue;
            ushort* hrow = h + (size_t)(base + rexp) * FDIM + ct * 128;
#pragma unroll
            for (int n = 0; n < 4; ++n) {
                int col = wn * 64 + n * 16 + (lane & 15);
                float v = acc[m][n][r] + b1e[col];
                float si = v / (1.f + __expf(-v));
                hrow[col] = f2bf(si);
            }
        }
    }
#undef STAGE1
#undef COMPUTE1
}

// ---- GEMM2: y[row] = h[row] @ w2t[e]^T + b2[e]   [M=ne, N=1024, K=4096] -----
__global__ __launch_bounds__(256) void k_gemm2(const ushort* __restrict__ h,
                                               const ushort* __restrict__ w2t,
                                               const float* __restrict__ b2,
                                               const int* __restrict__ cnt,
                                               const int* __restrict__ offs,
                                               ushort* __restrict__ y) {
    int bid = blockIdx.x;
    int e  = bid >> 9;           // 8 ct * 64 rt per expert
    int ct = (bid >> 6) & 7;
    int rt = bid & 63;
    int ne = cnt[e];
    if (rt * 128 >= ne) return;
    int base = offs[e];

    __shared__ __align__(16) ushort As[2][128 * 64];
    __shared__ __align__(16) ushort Bs[2][128 * 64];

    int tid = threadIdx.x, lane = tid & 63, wid = tid >> 6;
    int wm = wid >> 1, wn = wid & 1;

    const ushort* asrc[4];
    const ushort* bsrc[4];
    int coff[4];
    const ushort* w2e = w2t + (size_t)e * DIM * FDIM;
#pragma unroll
    for (int g = 0; g < 4; ++g) {
        int c = wid * 4 + g;
        int o = c * 1024 + lane * 16;
        int row = o >> 7;
        int ko  = (o & 127) >> 1;
        int grow = base + rt * 128 + row;
        grow = grow < TKROWS ? grow : TKROWS - 1;
        asrc[g] = h + (size_t)grow * FDIM + ko;
        bsrc[g] = w2e + (size_t)(ct * 128 + row) * FDIM + ko;
        coff[g] = c * 512;
    }

    f32x4 acc[4][4] = {};
#define STAGE2(buf, kt)                                                        \
    do {                                                                       \
        _Pragma("unroll")                                                      \
        for (int g = 0; g < 4; ++g) GLDS16(asrc[g] + (kt) * 64, &As[buf][coff[g]]); \
        _Pragma("unroll")                                                      \
        for (int g = 0; g < 4; ++g) GLDS16(bsrc[g] + (kt) * 64, &Bs[buf][coff[g]]); \
    } while (0)
#define COMPUTE2(buf)                                                          \
    do {                                                                       \
        _Pragma("unroll")                                                      \
        for (int ks = 0; ks < 2; ++ks) {                                       \
            s16x8 a[4], b[4];                                                  \
            _Pragma("unroll")                                                  \
            for (int m = 0; m < 4; ++m)                                        \
                a[m] = *(const s16x8*)&As[buf][(wm * 64 + m * 16 + (lane & 15)) * 64 + ks * 32 + (lane >> 4) * 8]; \
            _Pragma("unroll")                                                  \
            for (int n = 0; n < 4; ++n)                                        \
                b[n] = *(const s16x8*)&Bs[buf][(wn * 64 + n * 16 + (lane & 15)) * 64 + ks * 32 + (lane >> 4) * 8]; \
            _Pragma("unroll")                                                  \
            for (int m = 0; m < 4; ++m)                                        \
                _Pragma("unroll")                                              \
                for (int n = 0; n < 4; ++n)                                    \
                    acc[m][n] = __builtin_amdgcn_mfma_f32_16x16x32_bf16(a[m], b[n], acc[m][n], 0, 0, 0); \
        }                                                                      \
    } while (0)

    STAGE2(0, 0);
    int cur = 0;
    for (int kt = 0; kt < FDIM / 64 - 1; ++kt) {
        STAGE2(cur ^ 1, kt + 1);
        asm volatile("s_waitcnt vmcnt(8)" ::: "memory");
        __builtin_amdgcn_sched_barrier(0);
        __builtin_amdgcn_s_barrier();
        COMPUTE2(cur);
        __builtin_amdgcn_s_barrier();
        cur ^= 1;
    }
    asm volatile("s_waitcnt vmcnt(0)" ::: "memory");
    __builtin_amdgcn_sched_barrier(0);
    __builtin_amdgcn_s_barrier();
    COMPUTE2(cur);

    const float* b2e = b2 + e * DIM + ct * 128;
#pragma unroll
    for (int m = 0; m < 4; ++m) {
#pragma unroll
        for (int r = 0; r < 4; ++r) {
            int rloc = wm * 64 + m * 16 + ((lane >> 4) << 2) + r;
            int rexp = rt * 128 + rloc;
            if (rexp >= ne) continue;
            ushort* yrow = y + (size_t)(base + rexp) * DIM + ct * 128;
#pragma unroll
            for (int n = 0; n < 4; ++n) {
                int col = wn * 64 + n * 16 + (lane & 15);
                yrow[col] = f2bf(acc[m][n][r] + b2e[col]);
            }
        }
    }
#undef STAGE2
#undef COMPUTE2
}

// ---- combine: out[t] = w0*y[r0] + w1*y[r1] ----------------------------------
__global__ __launch_bounds__(256) void k_combine(const ushort* __restrict__ y,
                                                 const int* __restrict__ tok_row,
                                                 const float* __restrict__ w_arr,
                                                 float* __restrict__ out) {
    int gid = blockIdx.x * 256 + threadIdx.x;   // T_TOK*DIM/8 threads
    int t = gid >> 7;                            // 128 8-elem chunks per token
    int c = gid & 127;
    int r0 = tok_row[t * 2], r1 = tok_row[t * 2 + 1];
    float w0 = w_arr[t * 2], w1 = w_arr[t * 2 + 1];
    uint4 a = *(const uint4*)(y + (size_t)r0 * DIM + c * 8);
    uint4 b = *(const uint4*)(y + (size_t)r1 * DIM + c * 8);
    float4 o0, o1;
    o0.x = w0 * bf2f(a.x & 0xFFFF) + w1 * bf2f(b.x & 0xFFFF);
    o0.y = w0 * bf2f(a.x >> 16)    + w1 * bf2f(b.x >> 16);
    o0.z = w0 * bf2f(a.y & 0xFFFF) + w1 * bf2f(b.y & 0xFFFF);
    o0.w = w0 * bf2f(a.y >> 16)    + w1 * bf2f(b.y >> 16);
    o1.x = w0 * bf2f(a.z & 0xFFFF) + w1 * bf2f(b.z & 0xFFFF);
    o1.y = w0 * bf2f(a.z >> 16)    + w1 * bf2f(b.z >> 16);
    o1.z = w0 * bf2f(a.w & 0xFFFF) + w1 * bf2f(b.w & 0xFFFF);
    o1.w = w0 * bf2f(a.w >> 16)    + w1 * bf2f(b.w >> 16);
    float4* op = (float4*)(out + (size_t)t * DIM + c * 8);
    op[0] = o0;
    op[1] = o1;
}

extern "C" void kernel_launch(void* const* d_in, const int* in_sizes, int n_in,
                              void* d_out, int out_size, void* d_ws, size_t ws_size,
                              hipStream_t stream) {
    const float* x      = (const float*)d_in[0];
    const float* gate_w = (const float*)d_in[1];
    const float* gate_b = (const float*)d_in[2];
    const float* w1     = (const float*)d_in[3];
    const float* b1     = (const float*)d_in[4];
    const float* w2     = (const float*)d_in[5];
    const float* b2     = (const float*)d_in[6];
    float* out = (float*)d_out;

    char* ws = (char*)d_ws;
    size_t o = 0;
    ushort* h  = (ushort*)(ws + o); o += (size_t)TKROWS * FDIM * 2;      // 134 MB
    ushort* wt = (ushort*)(ws + o); o += (size_t)NEXP * DIM * FDIM * 2;  // 67 MB (w1t then w2t)
    ushort* y  = (ushort*)(ws + o);                                      // 33.5 MB
    ushort* xb = y;                 o += (size_t)TKROWS * DIM * 2;       // xb (16.8MB) dies before y is written
    int*   idx_arr   = (int*)(ws + o);   o += TKROWS * 4;
    float* w_arr     = (float*)(ws + o); o += TKROWS * 4;
    int*   row_token = (int*)(ws + o);   o += TKROWS * 4;
    int*   tok_row   = (int*)(ws + o);   o += TKROWS * 4;
    int*   cnt  = (int*)(ws + o);       // 8 ints
    int*   offs = cnt + 8;              // 9 ints
    int*   fill = cnt + 24;             // 8 ints

    hipMemsetAsync(cnt, 0, 256, stream);

    k_convert_x<<<4096, 256, 0, stream>>>((const float4*)x, (uint4*)xb);
    k_router<<<T_TOK / 4, 256, 0, stream>>>(x, gate_w, gate_b, idx_arr, w_arr, cnt);
    k_scan<<<1, 64, 0, stream>>>(cnt, offs);
    k_fill<<<T_TOK / 256, 256, 0, stream>>>(idx_arr, w_arr, offs, fill, row_token, tok_row);

    k_transpose<<<NEXP * (DIM / 64) * (FDIM / 64), 256, 0, stream>>>(w1, wt, DIM, FDIM);
    k_gemm1<<<NEXP * 64 * 32, 256, 0, stream>>>(xb, wt, b1, cnt, offs, row_token, h);
    k_transpose<<<NEXP * (FDIM / 64) * (DIM / 64), 256, 0, stream>>>(w2, wt, FDIM, DIM);
    k_gemm2<<<NEXP * 64 * 8, 256, 0, stream>>>(h, wt, b2, cnt, offs, y);
    k_combine<<<T_TOK * DIM / 8 / 256, 256, 0, stream>>>(y, tok_row, w_arr, out);
}

// Round 5
// 944.204 us; speedup vs baseline: 1.5388x; 1.3272x over previous
//
#include <hip/hip_runtime.h>
#include <hip/hip_bf16.h>
#include <stdint.h>

#define T_TOK 8192
#define DIM   1024
#define FDIM  4096
#define NEXP  8
#define TKROWS (T_TOK * 2)   // total routed rows (top-2)

typedef float f32x4 __attribute__((ext_vector_type(4)));
typedef short s16x8 __attribute__((ext_vector_type(8)));

#define GLDS16(g, l) __builtin_amdgcn_global_load_lds(                         \
    (const __attribute__((address_space(1))) void*)(g),                        \
    (__attribute__((address_space(3))) void*)(l), 16, 0, 0)

static __device__ __forceinline__ unsigned short f2bf(float f) {
    unsigned int u = __float_as_uint(f);
    unsigned int r = u + 0x7FFFu + ((u >> 16) & 1u);
    return (unsigned short)(r >> 16);
}
static __device__ __forceinline__ float bf2f(unsigned short s) {
    return __uint_as_float((unsigned int)s << 16);
}

// ---- x f32 -> bf16 ----------------------------------------------------------
__global__ __launch_bounds__(256) void k_convert_x(const float4* __restrict__ x,
                                                   uint4* __restrict__ xb) {
    int i = blockIdx.x * 256 + threadIdx.x;      // each thread: 8 floats
    float4 a = x[2 * i], b = x[2 * i + 1];
    uint4 o;
    o.x = f2bf(a.x) | ((unsigned)f2bf(a.y) << 16);
    o.y = f2bf(a.z) | ((unsigned)f2bf(a.w) << 16);
    o.z = f2bf(b.x) | ((unsigned)f2bf(b.y) << 16);
    o.w = f2bf(b.z) | ((unsigned)f2bf(b.w) << 16);
    xb[i] = o;
}

// ---- weight transpose+convert: w [E][K][N] f32 -> wt [E][N][K] bf16 ---------
__global__ __launch_bounds__(256) void k_transpose(const float* __restrict__ w,
                                                   ushort* __restrict__ wt,
                                                   int K, int N) {
    int nt = N >> 6, ktl = K >> 6;
    int bid = blockIdx.x;
    int e = bid / (ktl * nt);
    int r = bid % (ktl * nt);
    int kb = r / nt, nb = r % nt;
    __shared__ ushort tile[64][65];
    const float* we = w + (size_t)e * K * N + (size_t)(kb * 64) * N + nb * 64;
    int t = threadIdx.x;
#pragma unroll
    for (int g = 0; g < 4; ++g) {
        int idx = t + g * 256;
        int row = idx >> 4, c4 = idx & 15;
        float4 v = *(const float4*)(we + (size_t)row * N + c4 * 4);
        tile[row][c4 * 4 + 0] = f2bf(v.x);
        tile[row][c4 * 4 + 1] = f2bf(v.y);
        tile[row][c4 * 4 + 2] = f2bf(v.z);
        tile[row][c4 * 4 + 3] = f2bf(v.w);
    }
    __syncthreads();
    ushort* wte = wt + (size_t)e * K * N + (size_t)(nb * 64) * K + kb * 64;
#pragma unroll
    for (int g = 0; g < 4; ++g) {
        int idx = t + g * 256;
        int n = idx >> 4, k4 = idx & 15;
        ushort4 o4;
        o4.x = tile[k4 * 4 + 0][n];
        o4.y = tile[k4 * 4 + 1][n];
        o4.z = tile[k4 * 4 + 2][n];
        o4.w = tile[k4 * 4 + 3][n];
        *(ushort4*)(wte + (size_t)n * K + k4 * 4) = o4;
    }
}

// ---- router: softmax(x @ gate_w + gate_b), top-2 ----------------------------
__global__ __launch_bounds__(256) void k_router(const float* __restrict__ x,
                                                const float* __restrict__ gw,
                                                const float* __restrict__ gb,
                                                int* __restrict__ idx_arr,
                                                float* __restrict__ w_arr,
                                                int* __restrict__ cnt) {
    int lane = threadIdx.x & 63, w = threadIdx.x >> 6;
    int tok = blockIdx.x * 4 + w;
    const float* xr = x + (size_t)tok * DIM;
    float acc[8];
#pragma unroll
    for (int e = 0; e < 8; ++e) acc[e] = 0.f;
    for (int it = 0; it < DIM / 64; ++it) {
        int d = it * 64 + lane;
        float xv = xr[d];
        const float4* g = (const float4*)(gw + (size_t)d * 8);
        float4 g0 = g[0], g1 = g[1];
        acc[0] += xv * g0.x; acc[1] += xv * g0.y;
        acc[2] += xv * g0.z; acc[3] += xv * g0.w;
        acc[4] += xv * g1.x; acc[5] += xv * g1.y;
        acc[6] += xv * g1.z; acc[7] += xv * g1.w;
    }
#pragma unroll
    for (int off = 32; off; off >>= 1)
#pragma unroll
        for (int e = 0; e < 8; ++e) acc[e] += __shfl_xor(acc[e], off);
    if (lane == 0) {
        float l[8], m = -1e30f;
#pragma unroll
        for (int e = 0; e < 8; ++e) { l[e] = acc[e] + gb[e]; m = fmaxf(m, l[e]); }
        float s = 0.f, p[8];
#pragma unroll
        for (int e = 0; e < 8; ++e) { p[e] = expf(l[e] - m); s += p[e]; }
        float inv = 1.f / s;
#pragma unroll
        for (int e = 0; e < 8; ++e) p[e] *= inv;
        int i0 = 0;
#pragma unroll
        for (int e = 1; e < 8; ++e) if (p[e] > p[i0]) i0 = e;
        int i1 = (i0 == 0) ? 1 : 0;
#pragma unroll
        for (int e = 0; e < 8; ++e) if (e != i0 && p[e] > p[i1]) i1 = e;
        idx_arr[tok * 2 + 0] = i0;  w_arr[tok * 2 + 0] = p[i0];
        idx_arr[tok * 2 + 1] = i1;  w_arr[tok * 2 + 1] = p[i1];
        atomicAdd(&cnt[i0], 1);
        atomicAdd(&cnt[i1], 1);
    }
}

__global__ void k_scan(const int* __restrict__ cnt, int* __restrict__ offs) {
    if (threadIdx.x == 0) {
        int s = 0;
        for (int e = 0; e < NEXP; ++e) { offs[e] = s; s += cnt[e]; }
        offs[NEXP] = s;
    }
}

__global__ __launch_bounds__(256) void k_fill(const int* __restrict__ idx_arr,
                                              const float* __restrict__ w_arr,
                                              const int* __restrict__ offs,
                                              int* __restrict__ fill,
                                              int* __restrict__ row_token,
                                              int* __restrict__ tok_row) {
    int t = blockIdx.x * 256 + threadIdx.x;
    if (t >= T_TOK) return;
#pragma unroll
    for (int k = 0; k < 2; ++k) {
        int e = idx_arr[t * 2 + k];
        int slot = atomicAdd(&fill[e], 1);
        int r = offs[e] + slot;
        row_token[r] = t;
        tok_row[t * 2 + k] = r;
    }
}

// ============ 256x256 2-phase counted-vmcnt grouped GEMM =====================
// 512 thr = 8 waves (2M x 4N); per-wave C = 128x64 (acc[8][4]); BK=64.
// LDS 128 KB: As/Bs[2][256*64] ushort. 8 global_load_lds per thread per K-tile
// -> vmcnt(8) waits exactly the previous batch, next batch stays in flight.

#define STAGEG(AS, BS, buf, kt)                                                \
    do {                                                                       \
        _Pragma("unroll")                                                      \
        for (int g = 0; g < 4; ++g) GLDS16(asrc[g] + (kt) * 64, &AS[buf][coff[g]]); \
        _Pragma("unroll")                                                      \
        for (int g = 0; g < 4; ++g) GLDS16(bsrc[g] + (kt) * 64, &BS[buf][coff[g]]); \
    } while (0)

#define COMPUTEG(AS, BS, buf)                                                  \
    do {                                                                       \
        _Pragma("unroll")                                                      \
        for (int ks = 0; ks < 2; ++ks) {                                       \
            s16x8 a[8], b[4];                                                  \
            _Pragma("unroll")                                                  \
            for (int m = 0; m < 8; ++m)                                        \
                a[m] = *(const s16x8*)&AS[buf][(wm * 128 + m * 16 + (lane & 15)) * 64 + ks * 32 + (lane >> 4) * 8]; \
            _Pragma("unroll")                                                  \
            for (int n = 0; n < 4; ++n)                                        \
                b[n] = *(const s16x8*)&BS[buf][(wn * 64 + n * 16 + (lane & 15)) * 64 + ks * 32 + (lane >> 4) * 8]; \
            _Pragma("unroll")                                                  \
            for (int m = 0; m < 8; ++m)                                        \
                _Pragma("unroll")                                              \
                for (int n = 0; n < 4; ++n)                                    \
                    acc[m][n] = __builtin_amdgcn_mfma_f32_16x16x32_bf16(a[m], b[n], acc[m][n], 0, 0, 0); \
        }                                                                      \
    } while (0)

// ---- GEMM1: h = silu(x_gathered @ w1t[e]^T + b1[e])  [M=ne, N=4096, K=1024] -
__global__ __launch_bounds__(512) void k_gemm1(const ushort* __restrict__ xb,
                                               const ushort* __restrict__ w1t,
                                               const float* __restrict__ b1,
                                               const int* __restrict__ cnt,
                                               const int* __restrict__ offs,
                                               const int* __restrict__ row_token,
                                               ushort* __restrict__ h) {
    int bid = blockIdx.x;
    int e  = bid >> 10;          // 64 rt * 16 ct per expert
    int rt = (bid >> 4) & 63;
    int ct = bid & 15;
    int ne = cnt[e];
    if (rt * 256 >= ne) return;
    int base = offs[e];

    __shared__ __align__(16) ushort As[2][256 * 64];
    __shared__ __align__(16) ushort Bs[2][256 * 64];

    int tid = threadIdx.x, lane = tid & 63, wid = tid >> 6;
    int wm = wid >> 2, wn = wid & 3;

    const ushort* asrc[4];
    const ushort* bsrc[4];
    int coff[4];
    const ushort* w1e = w1t + (size_t)e * FDIM * DIM;
#pragma unroll
    for (int g = 0; g < 4; ++g) {
        int row = (tid >> 3) + g * 64;       // 0..255
        int ko  = (tid & 7) * 8;
        int grow = base + rt * 256 + row;
        grow = grow < TKROWS ? grow : TKROWS - 1;
        asrc[g] = xb + (size_t)row_token[grow] * DIM + ko;
        bsrc[g] = w1e + (size_t)(ct * 256 + row) * DIM + ko;
        coff[g] = wid * 512 + g * 4096;      // wave-uniform chunk base (+lane*16B by HW)
    }

    f32x4 acc[8][4] = {};
    STAGEG(As, Bs, 0, 0);
    int cur = 0;
    for (int kt = 0; kt < DIM / 64 - 1; ++kt) {
        STAGEG(As, Bs, cur ^ 1, kt + 1);              // 8 VMEM in flight
        asm volatile("s_waitcnt vmcnt(8)" ::: "memory");
        __builtin_amdgcn_sched_barrier(0);
        __builtin_amdgcn_s_barrier();                 // tile[cur] ready for all
        COMPUTEG(As, Bs, cur);
        __builtin_amdgcn_s_barrier();                 // done reading buf[cur]
        cur ^= 1;
    }
    asm volatile("s_waitcnt vmcnt(0)" ::: "memory");
    __builtin_amdgcn_sched_barrier(0);
    __builtin_amdgcn_s_barrier();
    COMPUTEG(As, Bs, cur);

    const float* b1e = b1 + e * FDIM + ct * 256;
#pragma unroll
    for (int m = 0; m < 8; ++m) {
#pragma unroll
        for (int r = 0; r < 4; ++r) {
            int rloc = wm * 128 + m * 16 + ((lane >> 4) << 2) + r;
            int rexp = rt * 256 + rloc;
            if (rexp >= ne) continue;
            ushort* hrow = h + (size_t)(base + rexp) * FDIM + ct * 256;
#pragma unroll
            for (int n = 0; n < 4; ++n) {
                int col = wn * 64 + n * 16 + (lane & 15);
                float v = acc[m][n][r] + b1e[col];
                float si = v / (1.f + __expf(-v));
                hrow[col] = f2bf(si);
            }
        }
    }
}

// ---- GEMM2: y[row] = h[row] @ w2t[e]^T + b2[e]   [M=ne, N=1024, K=4096] -----
__global__ __launch_bounds__(512) void k_gemm2(const ushort* __restrict__ h,
                                               const ushort* __restrict__ w2t,
                                               const float* __restrict__ b2,
                                               const int* __restrict__ cnt,
                                               const int* __restrict__ offs,
                                               ushort* __restrict__ y) {
    int bid = blockIdx.x;
    int e  = bid >> 8;           // 64 rt * 4 ct per expert
    int rt = (bid >> 2) & 63;
    int ct = bid & 3;
    int ne = cnt[e];
    if (rt * 256 >= ne) return;
    int base = offs[e];

    __shared__ __align__(16) ushort As[2][256 * 64];
    __shared__ __align__(16) ushort Bs[2][256 * 64];

    int tid = threadIdx.x, lane = tid & 63, wid = tid >> 6;
    int wm = wid >> 2, wn = wid & 3;

    const ushort* asrc[4];
    const ushort* bsrc[4];
    int coff[4];
    const ushort* w2e = w2t + (size_t)e * DIM * FDIM;
#pragma unroll
    for (int g = 0; g < 4; ++g) {
        int row = (tid >> 3) + g * 64;
        int ko  = (tid & 7) * 8;
        int grow = base + rt * 256 + row;
        grow = grow < TKROWS ? grow : TKROWS - 1;
        asrc[g] = h + (size_t)grow * FDIM + ko;
        bsrc[g] = w2e + (size_t)(ct * 256 + row) * FDIM + ko;
        coff[g] = wid * 512 + g * 4096;
    }

    f32x4 acc[8][4] = {};
    STAGEG(As, Bs, 0, 0);
    int cur = 0;
    for (int kt = 0; kt < FDIM / 64 - 1; ++kt) {
        STAGEG(As, Bs, cur ^ 1, kt + 1);
        asm volatile("s_waitcnt vmcnt(8)" ::: "memory");
        __builtin_amdgcn_sched_barrier(0);
        __builtin_amdgcn_s_barrier();
        COMPUTEG(As, Bs, cur);
        __builtin_amdgcn_s_barrier();
        cur ^= 1;
    }
    asm volatile("s_waitcnt vmcnt(0)" ::: "memory");
    __builtin_amdgcn_sched_barrier(0);
    __builtin_amdgcn_s_barrier();
    COMPUTEG(As, Bs, cur);

    const float* b2e = b2 + e * DIM + ct * 256;
#pragma unroll
    for (int m = 0; m < 8; ++m) {
#pragma unroll
        for (int r = 0; r < 4; ++r) {
            int rloc = wm * 128 + m * 16 + ((lane >> 4) << 2) + r;
            int rexp = rt * 256 + rloc;
            if (rexp >= ne) continue;
            ushort* yrow = y + (size_t)(base + rexp) * DIM + ct * 256;
#pragma unroll
            for (int n = 0; n < 4; ++n) {
                int col = wn * 64 + n * 16 + (lane & 15);
                yrow[col] = f2bf(acc[m][n][r] + b2e[col]);
            }
        }
    }
}

// ---- combine: out[t] = w0*y[r0] + w1*y[r1] ----------------------------------
__global__ __launch_bounds__(256) void k_combine(const ushort* __restrict__ y,
                                                 const int* __restrict__ tok_row,
                                                 const float* __restrict__ w_arr,
                                                 float* __restrict__ out) {
    int gid = blockIdx.x * 256 + threadIdx.x;   // T_TOK*DIM/8 threads
    int t = gid >> 7;                            // 128 8-elem chunks per token
    int c = gid & 127;
    int r0 = tok_row[t * 2], r1 = tok_row[t * 2 + 1];
    float w0 = w_arr[t * 2], w1 = w_arr[t * 2 + 1];
    uint4 a = *(const uint4*)(y + (size_t)r0 * DIM + c * 8);
    uint4 b = *(const uint4*)(y + (size_t)r1 * DIM + c * 8);
    float4 o0, o1;
    o0.x = w0 * bf2f(a.x & 0xFFFF) + w1 * bf2f(b.x & 0xFFFF);
    o0.y = w0 * bf2f(a.x >> 16)    + w1 * bf2f(b.x >> 16);
    o0.z = w0 * bf2f(a.y & 0xFFFF) + w1 * bf2f(b.y & 0xFFFF);
    o0.w = w0 * bf2f(a.y >> 16)    + w1 * bf2f(b.y >> 16);
    o1.x = w0 * bf2f(a.z & 0xFFFF) + w1 * bf2f(b.z & 0xFFFF);
    o1.y = w0 * bf2f(a.z >> 16)    + w1 * bf2f(b.z >> 16);
    o1.z = w0 * bf2f(a.w & 0xFFFF) + w1 * bf2f(b.w & 0xFFFF);
    o1.w = w0 * bf2f(a.w >> 16)    + w1 * bf2f(b.w >> 16);
    float4* op = (float4*)(out + (size_t)t * DIM + c * 8);
    op[0] = o0;
    op[1] = o1;
}

extern "C" void kernel_launch(void* const* d_in, const int* in_sizes, int n_in,
                              void* d_out, int out_size, void* d_ws, size_t ws_size,
                              hipStream_t stream) {
    const float* x      = (const float*)d_in[0];
    const float* gate_w = (const float*)d_in[1];
    const float* gate_b = (const float*)d_in[2];
    const float* w1     = (const float*)d_in[3];
    const float* b1     = (const float*)d_in[4];
    const float* w2     = (const float*)d_in[5];
    const float* b2     = (const float*)d_in[6];
    float* out = (float*)d_out;

    char* ws = (char*)d_ws;
    size_t o = 0;
    ushort* h  = (ushort*)(ws + o); o += (size_t)TKROWS * FDIM * 2;      // 134 MB
    ushort* wt = (ushort*)(ws + o); o += (size_t)NEXP * DIM * FDIM * 2;  // 67 MB (w1t then w2t)
    ushort* y  = (ushort*)(ws + o);                                      // 33.5 MB
    ushort* xb = y;                 o += (size_t)TKROWS * DIM * 2;       // xb (16.8MB) dies before y is written
    int*   idx_arr   = (int*)(ws + o);   o += TKROWS * 4;
    float* w_arr     = (float*)(ws + o); o += TKROWS * 4;
    int*   row_token = (int*)(ws + o);   o += TKROWS * 4;
    int*   tok_row   = (int*)(ws + o);   o += TKROWS * 4;
    int*   cnt  = (int*)(ws + o);       // 8 ints
    int*   offs = cnt + 8;              // 9 ints
    int*   fill = cnt + 24;             // 8 ints

    hipMemsetAsync(cnt, 0, 256, stream);

    k_convert_x<<<4096, 256, 0, stream>>>((const float4*)x, (uint4*)xb);
    k_router<<<T_TOK / 4, 256, 0, stream>>>(x, gate_w, gate_b, idx_arr, w_arr, cnt);
    k_scan<<<1, 64, 0, stream>>>(cnt, offs);
    k_fill<<<T_TOK / 256, 256, 0, stream>>>(idx_arr, w_arr, offs, fill, row_token, tok_row);

    k_transpose<<<NEXP * (DIM / 64) * (FDIM / 64), 256, 0, stream>>>(w1, wt, DIM, FDIM);
    k_gemm1<<<NEXP * 64 * 16, 512, 0, stream>>>(xb, wt, b1, cnt, offs, row_token, h);
    k_transpose<<<NEXP * (FDIM / 64) * (DIM / 64), 256, 0, stream>>>(w2, wt, FDIM, DIM);
    k_gemm2<<<NEXP * 64 * 4, 512, 0, stream>>>(h, wt, b2, cnt, offs, y);
    k_combine<<<T_TOK * DIM / 8 / 256, 256, 0, stream>>>(y, tok_row, w_arr, out);
}

// Round 6
// 867.703 us; speedup vs baseline: 1.6745x; 1.0882x over previous
//
#include <hip/hip_runtime.h>
#include <hip/hip_bf16.h>
#include <stdint.h>

#define T_TOK 8192
#define DIM   1024
#define FDIM  4096
#define NEXP  8
#define TKROWS (T_TOK * 2)   // total routed rows (top-2)

typedef float f32x4 __attribute__((ext_vector_type(4)));
typedef short s16x8 __attribute__((ext_vector_type(8)));

#define GLDS16(g, l) __builtin_amdgcn_global_load_lds(                         \
    (const __attribute__((address_space(1))) void*)(g),                        \
    (__attribute__((address_space(3))) void*)(l), 16, 0, 0)

static __device__ __forceinline__ unsigned short f2bf(float f) {
    unsigned int u = __float_as_uint(f);
    unsigned int r = u + 0x7FFFu + ((u >> 16) & 1u);
    return (unsigned short)(r >> 16);
}
static __device__ __forceinline__ float bf2f(unsigned short s) {
    return __uint_as_float((unsigned int)s << 16);
}

// ---- x f32 -> bf16 ----------------------------------------------------------
__global__ __launch_bounds__(256) void k_convert_x(const float4* __restrict__ x,
                                                   uint4* __restrict__ xb) {
    int i = blockIdx.x * 256 + threadIdx.x;      // each thread: 8 floats
    float4 a = x[2 * i], b = x[2 * i + 1];
    uint4 o;
    o.x = f2bf(a.x) | ((unsigned)f2bf(a.y) << 16);
    o.y = f2bf(a.z) | ((unsigned)f2bf(a.w) << 16);
    o.z = f2bf(b.x) | ((unsigned)f2bf(b.y) << 16);
    o.w = f2bf(b.z) | ((unsigned)f2bf(b.w) << 16);
    xb[i] = o;
}

// ---- weight transpose+convert: w [E][K][N] f32 -> wt [E][N][K] bf16 ---------
__global__ __launch_bounds__(256) void k_transpose(const float* __restrict__ w,
                                                   ushort* __restrict__ wt,
                                                   int K, int N) {
    int nt = N >> 6, ktl = K >> 6;
    int bid = blockIdx.x;
    int e = bid / (ktl * nt);
    int r = bid % (ktl * nt);
    int kb = r / nt, nb = r % nt;
    __shared__ ushort tile[64][65];
    const float* we = w + (size_t)e * K * N + (size_t)(kb * 64) * N + nb * 64;
    int t = threadIdx.x;
#pragma unroll
    for (int g = 0; g < 4; ++g) {
        int idx = t + g * 256;
        int row = idx >> 4, c4 = idx & 15;
        float4 v = *(const float4*)(we + (size_t)row * N + c4 * 4);
        tile[row][c4 * 4 + 0] = f2bf(v.x);
        tile[row][c4 * 4 + 1] = f2bf(v.y);
        tile[row][c4 * 4 + 2] = f2bf(v.z);
        tile[row][c4 * 4 + 3] = f2bf(v.w);
    }
    __syncthreads();
    ushort* wte = wt + (size_t)e * K * N + (size_t)(nb * 64) * K + kb * 64;
#pragma unroll
    for (int g = 0; g < 4; ++g) {
        int idx = t + g * 256;
        int n = idx >> 4, k4 = idx & 15;
        ushort4 o4;
        o4.x = tile[k4 * 4 + 0][n];
        o4.y = tile[k4 * 4 + 1][n];
        o4.z = tile[k4 * 4 + 2][n];
        o4.w = tile[k4 * 4 + 3][n];
        *(ushort4*)(wte + (size_t)n * K + k4 * 4) = o4;
    }
}

// ---- router: softmax(x @ gate_w + gate_b), top-2 ----------------------------
__global__ __launch_bounds__(256) void k_router(const float* __restrict__ x,
                                                const float* __restrict__ gw,
                                                const float* __restrict__ gb,
                                                int* __restrict__ idx_arr,
                                                float* __restrict__ w_arr,
                                                int* __restrict__ cnt) {
    int lane = threadIdx.x & 63, w = threadIdx.x >> 6;
    int tok = blockIdx.x * 4 + w;
    const float* xr = x + (size_t)tok * DIM;
    float acc[8];
#pragma unroll
    for (int e = 0; e < 8; ++e) acc[e] = 0.f;
    for (int it = 0; it < DIM / 64; ++it) {
        int d = it * 64 + lane;
        float xv = xr[d];
        const float4* g = (const float4*)(gw + (size_t)d * 8);
        float4 g0 = g[0], g1 = g[1];
        acc[0] += xv * g0.x; acc[1] += xv * g0.y;
        acc[2] += xv * g0.z; acc[3] += xv * g0.w;
        acc[4] += xv * g1.x; acc[5] += xv * g1.y;
        acc[6] += xv * g1.z; acc[7] += xv * g1.w;
    }
#pragma unroll
    for (int off = 32; off; off >>= 1)
#pragma unroll
        for (int e = 0; e < 8; ++e) acc[e] += __shfl_xor(acc[e], off);
    if (lane == 0) {
        float l[8], m = -1e30f;
#pragma unroll
        for (int e = 0; e < 8; ++e) { l[e] = acc[e] + gb[e]; m = fmaxf(m, l[e]); }
        float s = 0.f, p[8];
#pragma unroll
        for (int e = 0; e < 8; ++e) { p[e] = expf(l[e] - m); s += p[e]; }
        float inv = 1.f / s;
#pragma unroll
        for (int e = 0; e < 8; ++e) p[e] *= inv;
        int i0 = 0;
#pragma unroll
        for (int e = 1; e < 8; ++e) if (p[e] > p[i0]) i0 = e;
        int i1 = (i0 == 0) ? 1 : 0;
#pragma unroll
        for (int e = 0; e < 8; ++e) if (e != i0 && p[e] > p[i1]) i1 = e;
        idx_arr[tok * 2 + 0] = i0;  w_arr[tok * 2 + 0] = p[i0];
        idx_arr[tok * 2 + 1] = i1;  w_arr[tok * 2 + 1] = p[i1];
        atomicAdd(&cnt[i0], 1);
        atomicAdd(&cnt[i1], 1);
    }
}

__global__ void k_scan(const int* __restrict__ cnt, int* __restrict__ offs) {
    if (threadIdx.x == 0) {
        int s = 0;
        for (int e = 0; e < NEXP; ++e) { offs[e] = s; s += cnt[e]; }
        offs[NEXP] = s;
    }
}

__global__ __launch_bounds__(256) void k_fill(const int* __restrict__ idx_arr,
                                              const float* __restrict__ w_arr,
                                              const int* __restrict__ offs,
                                              int* __restrict__ fill,
                                              int* __restrict__ row_token,
                                              int* __restrict__ tok_row) {
    int t = blockIdx.x * 256 + threadIdx.x;
    if (t >= T_TOK) return;
#pragma unroll
    for (int k = 0; k < 2; ++k) {
        int e = idx_arr[t * 2 + k];
        int slot = atomicAdd(&fill[e], 1);
        int r = offs[e] + slot;
        row_token[r] = t;
        tok_row[t * 2 + k] = r;
    }
}

// ============ counted-vmcnt grouped GEMMs with T2 source-swizzle =============
// LDS tiles [R][64] ushort (128B rows). Swizzle convention: physical 16B slot
// s at LDS row r holds LOGICAL slot s ^ (r&7). Staging chunks are 8-row
// aligned, so r&7 == (lane>>3)&7 -> achieved purely by per-lane GLOBAL source
// offset ksw = ((l&7)^((l>>3)&7))*8 ushort (LDS dest stays linear, m173).
// ds_reads XOR the slot with (row&7) == (lane&7). 16-way conflict -> 2-way.

// ---- GEMM1: h = silu(x_gathered @ w1t[e]^T + b1[e])  [M=ne, N=4096, K=1024] -
// BM=256, BN=256, BK=64; 8 waves (2Mx4N); per-wave 128x64 (acc[8][4]).
__global__ __launch_bounds__(512) void k_gemm1(const ushort* __restrict__ xb,
                                               const ushort* __restrict__ w1t,
                                               const float* __restrict__ b1,
                                               const int* __restrict__ cnt,
                                               const int* __restrict__ offs,
                                               const int* __restrict__ row_token,
                                               ushort* __restrict__ h) {
    int bid = blockIdx.x;
    int e  = bid >> 10;          // 64 rt * 16 ct per expert
    int rt = (bid >> 4) & 63;
    int ct = bid & 15;
    int ne = cnt[e];
    if (rt * 256 >= ne) return;
    int base = offs[e];

    __shared__ __align__(16) ushort As[2][256 * 64];
    __shared__ __align__(16) ushort Bs[2][256 * 64];

    int tid = threadIdx.x, lane = tid & 63, wid = tid >> 6;
    int wm = wid >> 2, wn = wid & 3;
    int ksw = ((lane & 7) ^ ((lane >> 3) & 7)) * 8;   // swizzled source col (ushort)

    const ushort* asrc[4];
    const ushort* bsrc[4];
    int coff[4];
    const ushort* w1e = w1t + (size_t)e * FDIM * DIM;
#pragma unroll
    for (int g = 0; g < 4; ++g) {
        int row = wid * 8 + g * 64 + (lane >> 3);    // chunk = wid + g*8, 8 rows
        int grow = base + rt * 256 + row;
        grow = grow < TKROWS ? grow : TKROWS - 1;
        asrc[g] = xb + (size_t)row_token[grow] * DIM + ksw;
        bsrc[g] = w1e + (size_t)(ct * 256 + row) * DIM + ksw;
        coff[g] = wid * 512 + g * 4096;              // ushort offset of chunk base
    }

    f32x4 acc[8][4] = {};
#define STAGE1(buf, kt)                                                        \
    do {                                                                       \
        _Pragma("unroll")                                                      \
        for (int g = 0; g < 4; ++g) GLDS16(asrc[g] + (kt) * 64, &As[buf][coff[g]]); \
        _Pragma("unroll")                                                      \
        for (int g = 0; g < 4; ++g) GLDS16(bsrc[g] + (kt) * 64, &Bs[buf][coff[g]]); \
    } while (0)
#define COMPUTE1(buf)                                                          \
    do {                                                                       \
        _Pragma("unroll")                                                      \
        for (int ks = 0; ks < 2; ++ks) {                                       \
            int sx = (((ks * 4 + (lane >> 4)) ^ (lane & 7)) << 3);             \
            s16x8 a[8], b[4];                                                  \
            _Pragma("unroll")                                                  \
            for (int m = 0; m < 8; ++m)                                        \
                a[m] = *(const s16x8*)&As[buf][(wm * 128 + m * 16 + (lane & 15)) * 64 + sx]; \
            _Pragma("unroll")                                                  \
            for (int n = 0; n < 4; ++n)                                        \
                b[n] = *(const s16x8*)&Bs[buf][(wn * 64 + n * 16 + (lane & 15)) * 64 + sx]; \
            _Pragma("unroll")                                                  \
            for (int m = 0; m < 8; ++m)                                        \
                _Pragma("unroll")                                              \
                for (int n = 0; n < 4; ++n)                                    \
                    acc[m][n] = __builtin_amdgcn_mfma_f32_16x16x32_bf16(a[m], b[n], acc[m][n], 0, 0, 0); \
        }                                                                      \
    } while (0)

    STAGE1(0, 0);
    int cur = 0;
    for (int kt = 0; kt < DIM / 64 - 1; ++kt) {
        STAGE1(cur ^ 1, kt + 1);                      // 8 VMEM in flight
        asm volatile("s_waitcnt vmcnt(8)" ::: "memory");
        __builtin_amdgcn_sched_barrier(0);
        __builtin_amdgcn_s_barrier();
        COMPUTE1(cur);
        __builtin_amdgcn_s_barrier();
        cur ^= 1;
    }
    asm volatile("s_waitcnt vmcnt(0)" ::: "memory");
    __builtin_amdgcn_sched_barrier(0);
    __builtin_amdgcn_s_barrier();
    COMPUTE1(cur);

    const float* b1e = b1 + e * FDIM + ct * 256;
#pragma unroll
    for (int m = 0; m < 8; ++m) {
#pragma unroll
        for (int r = 0; r < 4; ++r) {
            int rloc = wm * 128 + m * 16 + ((lane >> 4) << 2) + r;
            int rexp = rt * 256 + rloc;
            if (rexp >= ne) continue;
            ushort* hrow = h + (size_t)(base + rexp) * FDIM + ct * 256;
#pragma unroll
            for (int n = 0; n < 4; ++n) {
                int col = wn * 64 + n * 16 + (lane & 15);
                float v = acc[m][n][r] + b1e[col];
                float si = v / (1.f + __expf(-v));
                hrow[col] = f2bf(si);
            }
        }
    }
#undef STAGE1
#undef COMPUTE1
}

// ---- GEMM2: y[row] = h[row] @ w2t[e]^T + b2[e]   [M=ne, N=1024, K=4096] -----
// BM=128, BN=256 (512 active blocks -> 2 balanced CU rounds). 6 loads/K-tile.
__global__ __launch_bounds__(512) void k_gemm2(const ushort* __restrict__ h,
                                               const ushort* __restrict__ w2t,
                                               const float* __restrict__ b2,
                                               const int* __restrict__ cnt,
                                               const int* __restrict__ offs,
                                               ushort* __restrict__ y) {
    int bid = blockIdx.x;
    int e  = bid >> 9;           // 128 rt * 4 ct per expert
    int rt = (bid >> 2) & 127;
    int ct = bid & 3;
    int ne = cnt[e];
    if (rt * 128 >= ne) return;
    int base = offs[e];

    __shared__ __align__(16) ushort As[2][128 * 64];   // 32 KB
    __shared__ __align__(16) ushort Bs[2][256 * 64];   // 64 KB

    int tid = threadIdx.x, lane = tid & 63, wid = tid >> 6;
    int wm = wid >> 2, wn = wid & 3;
    int ksw = ((lane & 7) ^ ((lane >> 3) & 7)) * 8;

    const ushort* asrc[2];
    const ushort* bsrc[4];
    int acoff[2], bcoff[4];
    const ushort* w2e = w2t + (size_t)e * DIM * FDIM;
#pragma unroll
    for (int g = 0; g < 2; ++g) {
        int row = wid * 16 + g * 8 + (lane >> 3);    // chunk = wid*2+g
        int grow = base + rt * 128 + row;
        grow = grow < TKROWS ? grow : TKROWS - 1;
        asrc[g] = h + (size_t)grow * FDIM + ksw;
        acoff[g] = wid * 1024 + g * 512;
    }
#pragma unroll
    for (int g = 0; g < 4; ++g) {
        int row = wid * 32 + g * 8 + (lane >> 3);    // chunk = wid*4+g
        bsrc[g] = w2e + (size_t)(ct * 256 + row) * FDIM + ksw;
        bcoff[g] = wid * 2048 + g * 512;
    }

    f32x4 acc[4][4] = {};
#define STAGE2(buf, kt)                                                        \
    do {                                                                       \
        _Pragma("unroll")                                                      \
        for (int g = 0; g < 2; ++g) GLDS16(asrc[g] + (kt) * 64, &As[buf][acoff[g]]); \
        _Pragma("unroll")                                                      \
        for (int g = 0; g < 4; ++g) GLDS16(bsrc[g] + (kt) * 64, &Bs[buf][bcoff[g]]); \
    } while (0)
#define COMPUTE2(buf)                                                          \
    do {                                                                       \
        _Pragma("unroll")                                                      \
        for (int ks = 0; ks < 2; ++ks) {                                       \
            int sx = (((ks * 4 + (lane >> 4)) ^ (lane & 7)) << 3);             \
            s16x8 a[4], b[4];                                                  \
            _Pragma("unroll")                                                  \
            for (int m = 0; m < 4; ++m)                                        \
                a[m] = *(const s16x8*)&As[buf][(wm * 64 + m * 16 + (lane & 15)) * 64 + sx]; \
            _Pragma("unroll")                                                  \
            for (int n = 0; n < 4; ++n)                                        \
                b[n] = *(const s16x8*)&Bs[buf][(wn * 64 + n * 16 + (lane & 15)) * 64 + sx]; \
            _Pragma("unroll")                                                  \
            for (int m = 0; m < 4; ++m)                                        \
                _Pragma("unroll")                                              \
                for (int n = 0; n < 4; ++n)                                    \
                    acc[m][n] = __builtin_amdgcn_mfma_f32_16x16x32_bf16(a[m], b[n], acc[m][n], 0, 0, 0); \
        }                                                                      \
    } while (0)

    STAGE2(0, 0);
    int cur = 0;
    for (int kt = 0; kt < FDIM / 64 - 1; ++kt) {
        STAGE2(cur ^ 1, kt + 1);                      // 6 VMEM in flight
        asm volatile("s_waitcnt vmcnt(6)" ::: "memory");
        __builtin_amdgcn_sched_barrier(0);
        __builtin_amdgcn_s_barrier();
        COMPUTE2(cur);
        __builtin_amdgcn_s_barrier();
        cur ^= 1;
    }
    asm volatile("s_waitcnt vmcnt(0)" ::: "memory");
    __builtin_amdgcn_sched_barrier(0);
    __builtin_amdgcn_s_barrier();
    COMPUTE2(cur);

    const float* b2e = b2 + e * DIM + ct * 256;
#pragma unroll
    for (int m = 0; m < 4; ++m) {
#pragma unroll
        for (int r = 0; r < 4; ++r) {
            int rloc = wm * 64 + m * 16 + ((lane >> 4) << 2) + r;
            int rexp = rt * 128 + rloc;
            if (rexp >= ne) continue;
            ushort* yrow = y + (size_t)(base + rexp) * DIM + ct * 256;
#pragma unroll
            for (int n = 0; n < 4; ++n) {
                int col = wn * 64 + n * 16 + (lane & 15);
                yrow[col] = f2bf(acc[m][n][r] + b2e[col]);
            }
        }
    }
#undef STAGE2
#undef COMPUTE2
}

// ---- combine: out[t] = w0*y[r0] + w1*y[r1] ----------------------------------
__global__ __launch_bounds__(256) void k_combine(const ushort* __restrict__ y,
                                                 const int* __restrict__ tok_row,
                                                 const float* __restrict__ w_arr,
                                                 float* __restrict__ out) {
    int gid = blockIdx.x * 256 + threadIdx.x;   // T_TOK*DIM/8 threads
    int t = gid >> 7;                            // 128 8-elem chunks per token
    int c = gid & 127;
    int r0 = tok_row[t * 2], r1 = tok_row[t * 2 + 1];
    float w0 = w_arr[t * 2], w1 = w_arr[t * 2 + 1];
    uint4 a = *(const uint4*)(y + (size_t)r0 * DIM + c * 8);
    uint4 b = *(const uint4*)(y + (size_t)r1 * DIM + c * 8);
    float4 o0, o1;
    o0.x = w0 * bf2f(a.x & 0xFFFF) + w1 * bf2f(b.x & 0xFFFF);
    o0.y = w0 * bf2f(a.x >> 16)    + w1 * bf2f(b.x >> 16);
    o0.z = w0 * bf2f(a.y & 0xFFFF) + w1 * bf2f(b.y & 0xFFFF);
    o0.w = w0 * bf2f(a.y >> 16)    + w1 * bf2f(b.y >> 16);
    o1.x = w0 * bf2f(a.z & 0xFFFF) + w1 * bf2f(b.z & 0xFFFF);
    o1.y = w0 * bf2f(a.z >> 16)    + w1 * bf2f(b.z >> 16);
    o1.z = w0 * bf2f(a.w & 0xFFFF) + w1 * bf2f(b.w & 0xFFFF);
    o1.w = w0 * bf2f(a.w >> 16)    + w1 * bf2f(b.w >> 16);
    float4* op = (float4*)(out + (size_t)t * DIM + c * 8);
    op[0] = o0;
    op[1] = o1;
}

extern "C" void kernel_launch(void* const* d_in, const int* in_sizes, int n_in,
                              void* d_out, int out_size, void* d_ws, size_t ws_size,
                              hipStream_t stream) {
    const float* x      = (const float*)d_in[0];
    const float* gate_w = (const float*)d_in[1];
    const float* gate_b = (const float*)d_in[2];
    const float* w1     = (const float*)d_in[3];
    const float* b1     = (const float*)d_in[4];
    const float* w2     = (const float*)d_in[5];
    const float* b2     = (const float*)d_in[6];
    float* out = (float*)d_out;

    char* ws = (char*)d_ws;
    size_t o = 0;
    ushort* h  = (ushort*)(ws + o); o += (size_t)TKROWS * FDIM * 2;      // 134 MB
    ushort* wt = (ushort*)(ws + o); o += (size_t)NEXP * DIM * FDIM * 2;  // 67 MB (w1t then w2t)
    ushort* y  = (ushort*)(ws + o);                                      // 33.5 MB
    ushort* xb = y;                 o += (size_t)TKROWS * DIM * 2;       // xb (16.8MB) dies before y is written
    int*   idx_arr   = (int*)(ws + o);   o += TKROWS * 4;
    float* w_arr     = (float*)(ws + o); o += TKROWS * 4;
    int*   row_token = (int*)(ws + o);   o += TKROWS * 4;
    int*   tok_row   = (int*)(ws + o);   o += TKROWS * 4;
    int*   cnt  = (int*)(ws + o);       // 8 ints
    int*   offs = cnt + 8;              // 9 ints
    int*   fill = cnt + 24;             // 8 ints

    hipMemsetAsync(cnt, 0, 256, stream);

    k_convert_x<<<4096, 256, 0, stream>>>((const float4*)x, (uint4*)xb);
    k_router<<<T_TOK / 4, 256, 0, stream>>>(x, gate_w, gate_b, idx_arr, w_arr, cnt);
    k_scan<<<1, 64, 0, stream>>>(cnt, offs);
    k_fill<<<T_TOK / 256, 256, 0, stream>>>(idx_arr, w_arr, offs, fill, row_token, tok_row);

    k_transpose<<<NEXP * (DIM / 64) * (FDIM / 64), 256, 0, stream>>>(w1, wt, DIM, FDIM);
    k_gemm1<<<NEXP * 64 * 16, 512, 0, stream>>>(xb, wt, b1, cnt, offs, row_token, h);
    k_transpose<<<NEXP * (FDIM / 64) * (DIM / 64), 256, 0, stream>>>(w2, wt, FDIM, DIM);
    k_gemm2<<<NEXP * 128 * 4, 512, 0, stream>>>(h, wt, b2, cnt, offs, y);
    k_combine<<<T_TOK * DIM / 8 / 256, 256, 0, stream>>>(y, tok_row, w_arr, out);
}